// Round 1
// baseline (156.728 us; speedup 1.0000x reference)
//
#include <hip/hip_runtime.h>
#include <math.h>

// Network_22892175688023 — round 11: mega-fusion. 3 stages (was 7).
//   K1 k_prep_enc1 : E-planes (E1 hi+lo, E2/E3 hi) + Xs frags + enc L1 VALU (576 blk) [unchanged]
//   K2 k_enc2      : reduce slots1, bn1+relu, enc L2, slots2              (64 blk)    [unchanged]
//   K3 k_mega      : per-msub (16 rows, 8 waves): gate -> gen1+blend ->
//                    A1 frags (LDS) -> gen2+blend -> A2 frags (LDS) ->
//                    gen3 + cross-expert reduce -> out                    (64 blk x 512)
//   All MFMA accumulation chains and blend orders identical to R9 kernel -> same numerics.
//   p buffer / A-plane global round-trips (~32 MB) eliminated; bcg now block-local LDS.

#define DIN 103
#define NE  8
#define HH  256
#define DOUT 51
#define EPSBN 1e-5f

typedef __attribute__((ext_vector_type(8))) short bf16x8;
typedef __attribute__((ext_vector_type(4))) float f32x4;
typedef __attribute__((ext_vector_type(8))) unsigned short us8;
typedef unsigned short ushort_t;

__device__ __forceinline__ float eluf(float v) { return v > 0.f ? v : (expf(v) - 1.f); }
__device__ __forceinline__ unsigned short bf16h(float f) {
  unsigned u = __float_as_uint(f);
  u += 0x7FFFu + ((u >> 16) & 1u);
  return (unsigned short)(u >> 16);
}
__device__ __forceinline__ float bf16f(unsigned short h) { return __uint_as_float(((unsigned)h) << 16); }
__device__ __forceinline__ void split_bf16(float v, unsigned short& h, unsigned short& l) {
  h = bf16h(v);
  l = bf16h(v - bf16f(h));
}
#define MFMA __builtin_amdgcn_mfma_f32_16x16x32_bf16

// ---- ws layout (float offsets) — unchanged from R9/R10 ----
#define O_SLOTS1 0        // [64][128]
#define O_SLOTS2 8192     // [64][64]
#define O_H1RAW  20480    // [1024][64]
#define O_H2RAW  86016    // [1024][32]
#define O_XSH    118784   // [64 msub][4 kc][512] sh
#define O_XSL    184320
#define O_E1H    258048   // [8 e][16 ns][4 kc][512] sh
#define O_E1L    389120
#define O_E2H    520192   // [8 e][16 ns][8 kc][512] sh  (hi only)
#define O_E3H    782336   // [8 e][4 ns][8 kc][512] sh   (hi only)

// ================= K1: prep planes + Xs frags + enc L1 (VALU) =================
// blocks: E2 0..255 | E1 256..383 | E3 384..447 | Xs 448..511 | enc1 512..575
__global__ __launch_bounds__(256) void k_prep_enc1(
    const float* __restrict__ x, const float* __restrict__ w1, const float* __restrict__ b1,
    const float* __restrict__ ew1, const float* __restrict__ ew2, const float* __restrict__ ew3,
    float* __restrict__ ws) {
  __shared__ union {
    float tile[32][65];
    float xt[16][104];
    struct { float w1L[64 * DIN]; float xr[16][104]; float hb[16][64]; } e1;
  } sm;
  int bk = blockIdx.x, t = threadIdx.x;
  int l2 = t & 63, c = l2 & 15, q = l2 >> 4;

  if (bk < 256) {          // ---- E2: K=256, N=256, hi only ----
    int nh = bk & 3, kc = (bk >> 2) & 7, e = bk >> 5;
    int k0 = kc * 32, n0 = nh * 64;
#pragma unroll
    for (int i = 0; i < 8; ++i) {
      int kl = (t >> 6) + i * 4;
      sm.tile[kl][t & 63] = ew2[((size_t)e * HH + k0 + kl) * HH + n0 + (t & 63)];
    }
    __syncthreads();
    int nsl = t >> 6;
    us8 H8;
#pragma unroll
    for (int j = 0; j < 8; ++j) H8[j] = bf16h(sm.tile[q * 8 + j][nsl * 16 + c]);
    size_t dst = (((size_t)(e * 16 + nh * 4 + nsl)) * 8 + kc) * 512 + l2 * 8;
    *(us8*)((ushort_t*)(ws + O_E2H) + dst) = H8;
  } else if (bk < 384) {   // ---- E1: K=103->128, N=256, hi+lo ----
    int b2 = bk - 256;
    int nh = b2 & 3, kc = (b2 >> 2) & 3, e = b2 >> 4;
    int k0 = kc * 32, n0 = nh * 64;
#pragma unroll
    for (int i = 0; i < 8; ++i) {
      int kl = (t >> 6) + i * 4;
      int k = k0 + kl;
      sm.tile[kl][t & 63] = (k < DIN) ? ew1[((size_t)e * DIN + k) * HH + n0 + (t & 63)] : 0.f;
    }
    __syncthreads();
    int nsl = t >> 6;
    us8 H8, L8;
#pragma unroll
    for (int j = 0; j < 8; ++j) {
      unsigned short h, lo; split_bf16(sm.tile[q * 8 + j][nsl * 16 + c], h, lo);
      H8[j] = h; L8[j] = lo;
    }
    size_t dst = (((size_t)(e * 16 + nh * 4 + nsl)) * 4 + kc) * 512 + l2 * 8;
    *(us8*)((ushort_t*)(ws + O_E1H) + dst) = H8;
    *(us8*)((ushort_t*)(ws + O_E1L) + dst) = L8;
  } else if (bk < 448) {   // ---- E3: K=256, N=51->64, hi only ----
    int b2 = bk - 384;
    int kc = b2 & 7, e = b2 >> 3;
    int k0 = kc * 32;
#pragma unroll
    for (int i = 0; i < 8; ++i) {
      int kl = (t >> 6) + i * 4;
      int n = t & 63;
      sm.tile[kl][n] = (n < DOUT) ? ew3[((size_t)e * HH + k0 + kl) * DOUT + n] : 0.f;
    }
    __syncthreads();
    int nsl = t >> 6;
    us8 H8;
#pragma unroll
    for (int j = 0; j < 8; ++j) H8[j] = bf16h(sm.tile[q * 8 + j][nsl * 16 + c]);
    size_t dst = (((size_t)(e * 4 + nsl)) * 8 + kc) * 512 + l2 * 8;
    *(us8*)((ushort_t*)(ws + O_E3H) + dst) = H8;
  } else if (bk < 512) {   // ---- Xs: A-fragments of scaled x, 16 rows/block, hi+lo ----
    int msub = bk - 448;
    for (int i = t; i < 16 * 104; i += 256) {
      int b = i / 104, k = i - b * 104;
      float v = 0.f;
      if (k < DIN) { v = x[(size_t)(msub * 16 + b) * DIN + k]; if (k >= 100) v *= 100.f; }
      sm.xt[b][k] = v;
    }
    __syncthreads();
    int kc = t >> 6;
    int m = c;
    us8 H8, L8;
#pragma unroll
    for (int j = 0; j < 8; ++j) {
      int k = kc * 32 + q * 8 + j;
      float v = (k < 104) ? sm.xt[m][k] : 0.f;
      unsigned short h, lo; split_bf16(v, h, lo);
      H8[j] = h; L8[j] = lo;
    }
    size_t dst = ((size_t)msub * 4 + kc) * 512 + l2 * 8;
    *(us8*)((ushort_t*)(ws + O_XSH) + dst) = H8;
    *(us8*)((ushort_t*)(ws + O_XSL) + dst) = L8;
  } else {                 // ---- enc L1 (VALU): 16 rows/block ----
    float* slots1 = ws + O_SLOTS1;
    float* h1raw  = ws + O_H1RAW;
    int bkl = bk - 512;
    int r0 = bkl * 16;
    for (int i = t; i < 64 * DIN; i += 256) sm.e1.w1L[i] = w1[i];
    for (int i = t; i < 16 * 104; i += 256) {
      int r = i / 104, c2 = i - r * 104;
      float v = 0.f;
      if (c2 < DIN) { v = x[(size_t)(r0 + r) * DIN + c2]; if (c2 >= 100) v *= 100.f; }
      sm.e1.xr[r][c2] = v;
    }
    __syncthreads();
#pragma unroll
    for (int i = 0; i < 4; ++i) {
      int idx = t + i * 256;
      int r = idx >> 6, j = idx & 63;
      float acc = b1[j];
      for (int k = 0; k < DIN; ++k) acc = fmaf(sm.e1.xr[r][k], sm.e1.w1L[j * DIN + k], acc);
      sm.e1.hb[r][j] = acc;
      h1raw[(size_t)(r0 + r) * 64 + j] = acc;
    }
    __syncthreads();
    if (t < 64) {
      float s = 0.f, qq = 0.f;
      for (int r = 0; r < 16; ++r) { float v = sm.e1.hb[r][t]; s += v; qq += v * v; }
      slots1[bkl * 128 + t] = s;
      slots1[bkl * 128 + 64 + t] = qq;
    }
  }
}

// ================= K2: reduce stats1, bn1+relu, enc L2 (VALU), slots2 =================
__global__ __launch_bounds__(256) void k_enc2(
    const float* __restrict__ gamma1, const float* __restrict__ beta1,
    const float* __restrict__ w2, const float* __restrict__ b2, float* __restrict__ ws) {
  __shared__ float w2T[64 * 33];
  __shared__ float red[128];
  __shared__ float sc1[64], sh1[64];
  __shared__ float h1b[16][64];
  __shared__ float hb2[16][32];
  float* slots1 = ws + O_SLOTS1;
  float* slots2 = ws + O_SLOTS2;
  float* h1raw  = ws + O_H1RAW;
  float* h2raw  = ws + O_H2RAW;
  int bk = blockIdx.x, t = threadIdx.x;
  int R0 = bk * 16;
  for (int i = t; i < 2048; i += 256) { int j = i >> 6, k = i & 63; w2T[k * 33 + j] = w2[i]; }
  if (t < 128) {
    float s = 0.f;
    for (int b = 0; b < 64; ++b) s += slots1[b * 128 + t];
    red[t] = s;
  }
  __syncthreads();
  if (t < 64) {
    float m = red[t] * (1.f / 1024.f);
    float v = red[64 + t] * (1.f / 1024.f) - m * m;
    float sc = gamma1[t] * rsqrtf(v + EPSBN);
    sc1[t] = sc; sh1[t] = beta1[t] - m * sc;
  }
  __syncthreads();
#pragma unroll
  for (int i = 0; i < 4; ++i) {
    int idx = t + i * 256;
    int r = idx >> 6, k = idx & 63;
    h1b[r][k] = fmaxf(fmaf(h1raw[(size_t)(R0 + r) * 64 + k], sc1[k], sh1[k]), 0.f);
  }
  __syncthreads();
#pragma unroll
  for (int i = 0; i < 2; ++i) {
    int o = t + i * 256;
    int r = o >> 5, j = o & 31;
    float acc = b2[j];
    for (int k = 0; k < 64; ++k) acc = fmaf(h1b[r][k], w2T[k * 33 + j], acc);
    hb2[r][j] = acc;
    h2raw[(size_t)(R0 + r) * 32 + j] = acc;
  }
  __syncthreads();
  if (t < 32) {
    float s = 0.f, q = 0.f;
    for (int r = 0; r < 16; ++r) { float v = hb2[r][t]; s += v; q += v * v; }
    slots2[bk * 64 + t] = s;
    slots2[bk * 64 + 32 + t] = q;
  }
}

// ================= K3: mega — gate + gen1/comb1 + gen2/comb2 + gen3/reduce =================
// 64 blocks (one per 16-row msub) x 512 threads (8 waves).
// LDS: union(gate 38.4K | staging 25.6K | p3s 34.8K) + A-frags 16K + bcL 0.5K = 55.4 KB.
__global__ __launch_bounds__(512) void k_mega(
    const float* __restrict__ gamma2, const float* __restrict__ beta2,
    const float* __restrict__ gw1, const float* __restrict__ gb1,
    const float* __restrict__ gw2, const float* __restrict__ gb2,
    const float* __restrict__ gw3, const float* __restrict__ gb3,
    const float* __restrict__ eb1, const float* __restrict__ eb2,
    const float* __restrict__ eb3,
    const float* __restrict__ ws, float* __restrict__ out) {
  __shared__ union {
    struct {                          // phase A: gate
      float gw1L[64 * 33];
      float gw2L[64 * 65];
      float gw3L[8 * 65];
      float gb1L[64], gb2L[64], gb3L[8];
      float red2[64], sc2[32], sh2[32];
      float lat[16][32];
      float g1[16][64], g2[16][64];
    } gate;
    struct {                          // phases B/C: blend staging (transposed) + eb tile
      float hT[256][17];              // [col(=k of next gemm)][row], stride 17 -> ~2-way banks
      float eb[2048];                 // eb1 / eb2 [8][256]
    } comb;
    struct {                          // phase D: per-expert partials + eb3
      float p3s[8][16][64];
      float eb3L[8][64];
    } g3;
  } U;
  __shared__ us8 aHv[512], aLv[512];  // A-fragments [kc][l2], reused A1 -> A2
  __shared__ float bcL[16][8];

  const int bk = blockIdx.x, t = threadIdx.x;
  const int wv = t >> 6, l = t & 63, c = l & 15, quad = l >> 4;
  const int R0 = bk * 16;
  const float* slots2 = ws + O_SLOTS2;
  const float* h2raw  = ws + O_H2RAW;
  const ushort_t* XsH = (const ushort_t*)(ws + O_XSH);
  const ushort_t* XsL = (const ushort_t*)(ws + O_XSL);
  const ushort_t* E1H = (const ushort_t*)(ws + O_E1H);
  const ushort_t* E1L = (const ushort_t*)(ws + O_E1L);
  const ushort_t* E2H = (const ushort_t*)(ws + O_E2H);
  const ushort_t* E3H = (const ushort_t*)(ws + O_E3H);

  // ---------- phase A: gate (bn2 + MLP + softmax) for this block's 16 rows ----------
  // identical math/order to R9's gate (which was 64 blocks x 16 rows) -> bit-identical bc
  for (int i = t; i < 2048; i += 512) { int j = i >> 5, k = i & 31; U.gate.gw1L[j * 33 + k] = gw1[i]; }
  for (int i = t; i < 4096; i += 512) { int j = i >> 6, k = i & 63; U.gate.gw2L[j * 65 + k] = gw2[i]; }
  { int j = t >> 6, k = t & 63; U.gate.gw3L[j * 65 + k] = gw3[t]; }
  if (t < 64) { U.gate.gb1L[t] = gb1[t]; U.gate.gb2L[t] = gb2[t]; }
  if (t < 8) U.gate.gb3L[t] = gb3[t];
  if (t < 64) {
    float s = 0.f;
    for (int b = 0; b < 64; ++b) s += slots2[b * 64 + t];
    U.gate.red2[t] = s;
  }
  __syncthreads();
  if (t < 32) {
    float m = U.gate.red2[t] * (1.f / 1024.f);
    float v = U.gate.red2[32 + t] * (1.f / 1024.f) - m * m;
    float sc = gamma2[t] * rsqrtf(v + EPSBN);
    U.gate.sc2[t] = sc; U.gate.sh2[t] = beta2[t] - m * sc;
  }
  __syncthreads();
  { int r = t >> 5, cc = t & 31;
    U.gate.lat[r][cc] = fmaxf(fmaf(h2raw[(size_t)(R0 + r) * 32 + cc], U.gate.sc2[cc], U.gate.sh2[cc]), 0.f); }
  __syncthreads();
#pragma unroll
  for (int rr = 0; rr < 2; ++rr) {
    int r = wv * 2 + rr;
    float a1 = U.gate.gb1L[l];
    for (int k = 0; k < 32; ++k) a1 = fmaf(U.gate.gw1L[l * 33 + k], U.gate.lat[r][k], a1);
    U.gate.g1[r][l] = eluf(a1);
  }
  __syncthreads();
#pragma unroll
  for (int rr = 0; rr < 2; ++rr) {
    int r = wv * 2 + rr;
    float a2 = U.gate.gb2L[l];
    for (int k = 0; k < 64; ++k) a2 = fmaf(U.gate.gw2L[l * 65 + k], U.gate.g1[r][k], a2);
    U.gate.g2[r][l] = eluf(a2);
  }
  __syncthreads();
#pragma unroll
  for (int rr = 0; rr < 2; ++rr) {
    int r = wv * 2 + rr;
    if (l < 8) {
      float a3 = U.gate.gb3L[l];
      for (int k = 0; k < 64; ++k) a3 = fmaf(U.gate.gw3L[l * 65 + k], U.gate.g2[r][k], a3);
      float mx = a3;
      mx = fmaxf(mx, __shfl_xor(mx, 1));
      mx = fmaxf(mx, __shfl_xor(mx, 2));
      mx = fmaxf(mx, __shfl_xor(mx, 4));
      float p = expf(a3 - mx);
      float sp = p;
      sp += __shfl_xor(sp, 1); sp += __shfl_xor(sp, 2); sp += __shfl_xor(sp, 4);
      bcL[r][l] = p / sp;
    }
  }
  __syncthreads();   // gate done: union may be reused; bcL live from here on

  // ---------- phase B: gen1 + inline comb1 -> A1 fragments in LDS ----------
  for (int i = t; i < 2048; i += 512) U.comb.eb[i] = eb1[i];
  bf16x8 a1h[4], a1l[4];
#pragma unroll
  for (int kc = 0; kc < 4; ++kc) {
    a1h[kc] = *(const bf16x8*)(XsH + ((size_t)bk * 4 + kc) * 512 + l * 8);
    a1l[kc] = *(const bf16x8*)(XsL + ((size_t)bk * 4 + kc) * 512 + l * 8);
  }
  __syncthreads();
  {
    f32x4 blend[2] = {};
#pragma unroll
    for (int e = 0; e < NE; ++e) {
      float bcv[4];
#pragma unroll
      for (int r = 0; r < 4; ++r) bcv[r] = bcL[quad * 4 + r][e];
#pragma unroll
      for (int nsi = 0; nsi < 2; ++nsi) {
        int ns = wv * 2 + nsi;
        f32x4 acc = {};
#pragma unroll
        for (int kc = 0; kc < 4; ++kc) {
          size_t bo = (((size_t)(e * 16 + ns)) * 4 + kc) * 512 + l * 8;
          bf16x8 bh = *(const bf16x8*)(E1H + bo);
          bf16x8 bl = *(const bf16x8*)(E1L + bo);
          acc = MFMA(a1h[kc], bh, acc, 0, 0, 0);
          acc = MFMA(a1l[kc], bh, acc, 0, 0, 0);
          acc = MFMA(a1h[kc], bl, acc, 0, 0, 0);
        }
        float ebv = U.comb.eb[e * HH + ns * 16 + c];
#pragma unroll
        for (int r = 0; r < 4; ++r) blend[nsi][r] = fmaf(bcv[r], acc[r] + ebv, blend[nsi][r]);
      }
    }
#pragma unroll
    for (int nsi = 0; nsi < 2; ++nsi) {
      int col = (wv * 2 + nsi) * 16 + c;
#pragma unroll
      for (int r = 0; r < 4; ++r) U.comb.hT[col][quad * 4 + r] = eluf(blend[nsi][r]);
    }
  }
  __syncthreads();
  {   // repack hT -> A1 fragments (hi+lo), t = kc*64 + l2
    int l2 = t & 63, row = l2 & 15, k0 = (t >> 6) * 32 + (l2 >> 4) * 8;
    us8 H, L;
#pragma unroll
    for (int j = 0; j < 8; ++j) {
      unsigned short h, lo; split_bf16(U.comb.hT[k0 + j][row], h, lo);
      H[j] = h; L[j] = lo;
    }
    aHv[t] = H; aLv[t] = L;
  }
  __syncthreads();

  // ---------- phase C: gen2 + inline comb2 -> A2 fragments in LDS ----------
  for (int i = t; i < 2048; i += 512) U.comb.eb[i] = eb2[i];
  bf16x8 a2h[8], a2l[8];        // hoist A1 frags: avoids 16x LDS re-read in e/nsi loops
#pragma unroll
  for (int kc = 0; kc < 8; ++kc) {
    a2h[kc] = *(const bf16x8*)&aHv[kc * 64 + l];
    a2l[kc] = *(const bf16x8*)&aLv[kc * 64 + l];
  }
  __syncthreads();
  {
    f32x4 blend[2] = {};
#pragma unroll
    for (int e = 0; e < NE; ++e) {
      float bcv[4];
#pragma unroll
      for (int r = 0; r < 4; ++r) bcv[r] = bcL[quad * 4 + r][e];
#pragma unroll
      for (int nsi = 0; nsi < 2; ++nsi) {
        int ns = wv * 2 + nsi;
        f32x4 acc = {};
#pragma unroll
        for (int kc = 0; kc < 8; ++kc) {
          size_t bo = (((size_t)(e * 16 + ns)) * 8 + kc) * 512 + l * 8;
          bf16x8 bh = *(const bf16x8*)(E2H + bo);
          acc = MFMA(a2h[kc], bh, acc, 0, 0, 0);
          acc = MFMA(a2l[kc], bh, acc, 0, 0, 0);
        }
        float ebv = U.comb.eb[e * HH + ns * 16 + c];
#pragma unroll
        for (int r = 0; r < 4; ++r) blend[nsi][r] = fmaf(bcv[r], acc[r] + ebv, blend[nsi][r]);
      }
    }
#pragma unroll
    for (int nsi = 0; nsi < 2; ++nsi) {
      int col = (wv * 2 + nsi) * 16 + c;
#pragma unroll
      for (int r = 0; r < 4; ++r) U.comb.hT[col][quad * 4 + r] = eluf(blend[nsi][r]);
    }
  }
  __syncthreads();
  {   // repack hT -> A2 fragments (overwrites A1 frags; all reads were from registers)
    int l2 = t & 63, row = l2 & 15, k0 = (t >> 6) * 32 + (l2 >> 4) * 8;
    us8 H, L;
#pragma unroll
    for (int j = 0; j < 8; ++j) {
      unsigned short h, lo; split_bf16(U.comb.hT[k0 + j][row], h, lo);
      H[j] = h; L[j] = lo;
    }
    aHv[t] = H; aLv[t] = L;
  }
  __syncthreads();

  // ---------- phase D: gen3 (wave = expert) + cross-expert reduce -> out ----------
  { int e = t >> 6, n = t & 63; U.g3.eb3L[e][n] = (n < DOUT) ? eb3[e * DOUT + n] : 0.f; }
  {
    const int e = wv;
    f32x4 acc[4] = {};
#pragma unroll
    for (int kc = 0; kc < 8; ++kc) {
      bf16x8 ah = *(const bf16x8*)&aHv[kc * 64 + l];
      bf16x8 al = *(const bf16x8*)&aLv[kc * 64 + l];
#pragma unroll
      for (int nsi = 0; nsi < 4; ++nsi) {
        size_t bo = (((size_t)(e * 4 + nsi)) * 8 + kc) * 512 + l * 8;
        bf16x8 bh = *(const bf16x8*)(E3H + bo);
        acc[nsi] = MFMA(ah, bh, acc[nsi], 0, 0, 0);
        acc[nsi] = MFMA(al, bh, acc[nsi], 0, 0, 0);
      }
    }
#pragma unroll
    for (int nsi = 0; nsi < 4; ++nsi)
#pragma unroll
      for (int r = 0; r < 4; ++r)
        U.g3.p3s[e][quad * 4 + r][nsi * 16 + c] = acc[nsi][r];
  }
  __syncthreads();
#pragma unroll
  for (int i = 0; i < 2; ++i) {
    int idx = t + i * 512;             // 1024 outputs: [16 rows][64 cols]
    int row = idx >> 6, col = idx & 63;
    float s = 0.f;
#pragma unroll
    for (int e2 = 0; e2 < 8; ++e2)
      s = fmaf(bcL[row][e2], U.g3.p3s[e2][row][col] + U.g3.eb3L[e2][col], s);
    if (col < DOUT) out[(size_t)(R0 + row) * DOUT + col] = s;
  }
}

extern "C" void kernel_launch(void* const* d_in, const int* in_sizes, int n_in,
                              void* d_out, int out_size, void* d_ws, size_t ws_size,
                              hipStream_t stream) {
  const float* x      = (const float*)d_in[0];
  const float* w1     = (const float*)d_in[1];
  const float* b1     = (const float*)d_in[2];
  const float* gamma1 = (const float*)d_in[3];
  const float* beta1  = (const float*)d_in[4];
  const float* w2     = (const float*)d_in[5];
  const float* b2     = (const float*)d_in[6];
  const float* gamma2 = (const float*)d_in[7];
  const float* beta2  = (const float*)d_in[8];
  const float* gw1    = (const float*)d_in[9];
  const float* gb1    = (const float*)d_in[10];
  const float* gw2    = (const float*)d_in[11];
  const float* gb2    = (const float*)d_in[12];
  const float* gw3    = (const float*)d_in[13];
  const float* gb3    = (const float*)d_in[14];
  const float* ew1    = (const float*)d_in[15];
  const float* eb1    = (const float*)d_in[16];
  const float* ew2    = (const float*)d_in[17];
  const float* eb2    = (const float*)d_in[18];
  const float* ew3    = (const float*)d_in[19];
  const float* eb3    = (const float*)d_in[20];
  float* wsf  = (float*)d_ws;
  float* outp = (float*)d_out;

  k_prep_enc1<<<576, 256, 0, stream>>>(x, w1, b1, ew1, ew2, ew3, wsf);
  k_enc2<<<64, 256, 0, stream>>>(gamma1, beta1, w2, b2, wsf);
  k_mega<<<64, 512, 0, stream>>>(gamma2, beta2, gw1, gb1, gw2, gb2, gw3, gb3,
                                 eb1, eb2, eb3, wsf, outp);
}